// Round 1
// baseline (726.870 us; speedup 1.0000x reference)
//
#include <hip/hip_runtime.h>
#include <math.h>

#define Bn 4
#define Ln 1024
#define Sn 1024
#define Hn 8
#define En 64

// ---------------------------------------------------------------------------
// K1: comm[b,h,l,s] = sum_e Q[b,l,h,e]K[b,s,h,e] - K[b,l,h,e]Q[b,s,h,e]
// written into the A region of d_out (used as scratch; K2 overwrites in place).
// Tiles: 64 (l) x 128 (s), 256 threads, 4x8 per-thread frags, E split in two
// 32-wide stages so static LDS stays at 55 KB. LDS stride 36 dwords keeps all
// read patterns at <=2-way bank aliasing (free on CDNA4).
// ---------------------------------------------------------------------------
__global__ __launch_bounds__(256) void k1_comm(const float* __restrict__ Q,
                                               const float* __restrict__ Kg,
                                               float* __restrict__ commOut) {
    __shared__ float Qi[64][36];
    __shared__ float Ki[64][36];
    __shared__ float Qj[128][36];
    __shared__ float Kj[128][36];

    const int st = blockIdx.x;   // 0..7   (128-wide s tile)
    const int lt = blockIdx.y;   // 0..15  (64-wide l tile)
    const int bh = blockIdx.z;   // b*8+h
    const int h = bh & 7;
    const int b = bh >> 3;
    const int tid = threadIdx.x;

    const int ty = tid >> 4;     // 0..15 : l rows 4*ty..4*ty+3
    const int tx = tid & 15;     // s = tx + 16*is, is in 0..7

    float acc[4][8];
#pragma unroll
    for (int i = 0; i < 4; ++i)
#pragma unroll
        for (int j = 0; j < 8; ++j) acc[i][j] = 0.f;

    for (int stg = 0; stg < 2; ++stg) {
        if (stg) __syncthreads();
        // stage i-side tiles (64 rows x 32 e)
#pragma unroll
        for (int i = 0; i < 2; ++i) {
            int f = tid + 256 * i;       // 0..511
            int r = f >> 3;              // 0..63
            int c = (f & 7) << 2;        // 0..28
            int e = stg * 32 + c;
            int row = lt * 64 + r;
            *reinterpret_cast<float4*>(&Qi[r][c]) =
                *reinterpret_cast<const float4*>(Q + (((size_t)b * Ln + row) * Hn + h) * En + e);
            *reinterpret_cast<float4*>(&Ki[r][c]) =
                *reinterpret_cast<const float4*>(Kg + (((size_t)b * Sn + row) * Hn + h) * En + e);
        }
        // stage j-side tiles (128 rows x 32 e)
#pragma unroll
        for (int i = 0; i < 4; ++i) {
            int f = tid + 256 * i;       // 0..1023
            int r = f >> 3;              // 0..127
            int c = (f & 7) << 2;
            int e = stg * 32 + c;
            int row = st * 128 + r;
            *reinterpret_cast<float4*>(&Qj[r][c]) =
                *reinterpret_cast<const float4*>(Q + (((size_t)b * Ln + row) * Hn + h) * En + e);
            *reinterpret_cast<float4*>(&Kj[r][c]) =
                *reinterpret_cast<const float4*>(Kg + (((size_t)b * Sn + row) * Hn + h) * En + e);
        }
        __syncthreads();

#pragma unroll
        for (int ec = 0; ec < 8; ++ec) {
            float4 a1[4], a2[4];
#pragma unroll
            for (int il = 0; il < 4; ++il) {
                a1[il] = *reinterpret_cast<const float4*>(&Qi[ty * 4 + il][ec * 4]);
                a2[il] = *reinterpret_cast<const float4*>(&Ki[ty * 4 + il][ec * 4]);
            }
#pragma unroll
            for (int is = 0; is < 8; ++is) {
                float4 b1 = *reinterpret_cast<const float4*>(&Kj[tx + 16 * is][ec * 4]);
                float4 b2 = *reinterpret_cast<const float4*>(&Qj[tx + 16 * is][ec * 4]);
#pragma unroll
                for (int il = 0; il < 4; ++il) {
                    float t = acc[il][is];
                    t += a1[il].x * b1.x - a2[il].x * b2.x;
                    t += a1[il].y * b1.y - a2[il].y * b2.y;
                    t += a1[il].z * b1.z - a2[il].z * b2.z;
                    t += a1[il].w * b1.w - a2[il].w * b2.w;
                    acc[il][is] = t;
                }
            }
        }
    }

    // epilogue: scalar stores, lanes tx contiguous in s -> coalesced 64B runs
#pragma unroll
    for (int il = 0; il < 4; ++il) {
        int gl = lt * 64 + ty * 4 + il;
        size_t base = (((size_t)b * Hn + h) * Ln + gl) * (size_t)Sn + st * 128;
#pragma unroll
        for (int is = 0; is < 8; ++is) {
            commOut[base + tx + 16 * is] = acc[il][is];
        }
    }
}

// ---------------------------------------------------------------------------
// K2: per (b,h,32-row l tile): read comm (A region), apply tanh/gelu/gumbel-
// sigmoid/hard-mask chain, write att back in place, accumulate row entropy and
// V = att @ value (LDS-staged att & value, 32-wide s chunks).
// ---------------------------------------------------------------------------
__global__ __launch_bounds__(256) void k2_fuse(float* __restrict__ A,
                                               const float* __restrict__ Vg,
                                               const float* __restrict__ phi,
                                               const float* __restrict__ u,
                                               const float* __restrict__ hard,
                                               const float* __restrict__ p_lg,
                                               const float* __restrict__ p_lt,
                                               const float* __restrict__ p_ltc,
                                               float* __restrict__ Vout,
                                               float* __restrict__ entOut) {
    __shared__ float att_lds[32][36];
    __shared__ float v_lds[32][68];
    __shared__ float ent_lds[32][8];

    const int b = blockIdx.x;
    const int h = blockIdx.y;
    const int lt = blockIdx.z;
    const int tid = threadIdx.x;

    const float gain = fminf(fmaxf(expf(p_lg[0]), 1e-3f), 1000.0f);
    const float tauc = fminf(fmaxf(expf(p_ltc[0]), 1e-3f), 10.0f);
    const float c1 = gain / tauc;
    const float tau = fminf(fmaxf(expf(p_lt[0]), 0.1f), 5.0f);
    const float itau = 1.0f / tau;

    const int tye = tid >> 3;   // 0..31 : l row (elementwise)
    const int txe = tid & 7;    // s float4 group
    const int tyv = tid >> 4;   // 0..15 : l rows tyv, tyv+16 (PV)
    const int txv = tid & 15;   // d float4 group

    float4 vacc0 = {0.f, 0.f, 0.f, 0.f};
    float4 vacc1 = {0.f, 0.f, 0.f, 0.f};
    float ent_acc = 0.f;

    const int gl = lt * 32 + tye;
    const size_t Abase = (((size_t)b * Hn + h) * Ln + gl) * (size_t)Sn;
    const size_t Pbase = ((size_t)h * Ln + gl) * (size_t)Sn;
    const size_t Mbase = (size_t)gl * (size_t)Sn;

    for (int sc = 0; sc < 32; ++sc) {
        const int s0 = sc * 32;
        // stage value[b, s0..s0+31, h, :]
#pragma unroll
        for (int i = 0; i < 2; ++i) {
            int f = tid + 256 * i;   // 0..511
            int r = f >> 4;          // 0..31
            int c = (f & 15) << 2;   // 0..60
            *reinterpret_cast<float4*>(&v_lds[r][c]) =
                *reinterpret_cast<const float4*>(Vg + (((size_t)b * Sn + (s0 + r)) * Hn + h) * En + c);
        }
        // elementwise chain on this thread's 4 elements
        const int gs = s0 + (txe << 2);
        float4 cm = *reinterpret_cast<const float4*>(A + Abase + gs);
        float4 ph = *reinterpret_cast<const float4*>(phi + Pbase + gs);
        float4 uu = *reinterpret_cast<const float4*>(u + Pbase + gs);
        float4 hm = *reinterpret_cast<const float4*>(hard + Mbase + gs);
        float4 att;
        {
            float cv[4] = {cm.x, cm.y, cm.z, cm.w};
            float pv[4] = {ph.x, ph.y, ph.z, ph.w};
            float uv[4] = {uu.x, uu.y, uu.z, uu.w};
            float hv[4] = {hm.x, hm.y, hm.z, hm.w};
            float av[4];
#pragma unroll
            for (int k = 0; k < 4; ++k) {
                float x = tanhf(c1 * cv[k]);
                float g = 0.5f * x * (1.0f + erff(x * 0.70710678118654752f));
                float a = 0.125f * g;  // scale = 1/sqrt(64)
                float z = (logf(uv[k] + 1e-8f) - logf(1.0f - uv[k] + 1e-8f) + pv[k]) * itau;
                float m = 1.0f / (1.0f + expf(-z));
                a *= m * hv[k];
                ent_acc += a * logf(fmaxf(a, 1e-8f));
                av[k] = a;
            }
            att.x = av[0]; att.y = av[1]; att.z = av[2]; att.w = av[3];
        }
        *reinterpret_cast<float4*>(A + Abase + gs) = att;   // in-place: A over comm
        *reinterpret_cast<float4*>(&att_lds[tye][txe << 2]) = att;
        __syncthreads();

        // PV: vacc[l, d] += att[l, s] * value[s, d]
#pragma unroll 8
        for (int s = 0; s < 32; ++s) {
            float a0 = att_lds[tyv][s];
            float a1 = att_lds[tyv + 16][s];
            float4 vv = *reinterpret_cast<const float4*>(&v_lds[s][txv << 2]);
            vacc0.x += a0 * vv.x; vacc0.y += a0 * vv.y; vacc0.z += a0 * vv.z; vacc0.w += a0 * vv.w;
            vacc1.x += a1 * vv.x; vacc1.y += a1 * vv.y; vacc1.z += a1 * vv.z; vacc1.w += a1 * vv.w;
        }
        __syncthreads();
    }

    // write V tile
    {
        int l0 = lt * 32 + tyv;
        int l1 = l0 + 16;
        *reinterpret_cast<float4*>(Vout + (((size_t)b * Ln + l0) * Hn + h) * En + (txv << 2)) = vacc0;
        *reinterpret_cast<float4*>(Vout + (((size_t)b * Ln + l1) * Hn + h) * En + (txv << 2)) = vacc1;
    }
    // entropy: reduce 8 partials per row, negate, nan_to_num
    ent_lds[tye][txe] = ent_acc;
    __syncthreads();
    if (tid < 32) {
        float ssum = 0.f;
#pragma unroll
        for (int j = 0; j < 8; ++j) ssum += ent_lds[tid][j];
        float e = -ssum;
        if (!(e == e)) e = 0.f;   // nan_to_num
        entOut[((size_t)b * Hn + h) * Ln + lt * 32 + tid] = e;
    }
}

extern "C" void kernel_launch(void* const* d_in, const int* in_sizes, int n_in,
                              void* d_out, int out_size, void* d_ws, size_t ws_size,
                              hipStream_t stream) {
    (void)in_sizes; (void)n_in; (void)d_ws; (void)ws_size; (void)out_size;

    const float* Q    = (const float*)d_in[0];   // (B,L,H,E)
    const float* K    = (const float*)d_in[1];   // (B,S,H,E)
    const float* Vv   = (const float*)d_in[2];   // (B,S,H,E)
    const float* phi  = (const float*)d_in[3];   // (H,L,S)
    const float* lg   = (const float*)d_in[4];   // scalar
    const float* ltau = (const float*)d_in[5];   // scalar
    const float* ltc  = (const float*)d_in[6];   // scalar
    const float* hard = (const float*)d_in[7];   // (L,S)
    const float* u    = (const float*)d_in[8];   // (H,L,S)
    // d_in[9..12] (mask_miss_k/q, pos, causal_mask) unused by reference

    float* out  = (float*)d_out;
    float* Vout = out;                                        // B*L*H*E
    float* Aout = out + (size_t)Bn * Ln * Hn * En;            // B*H*L*S
    float* ent  = Aout + (size_t)Bn * Hn * Ln * Sn;           // B*H*L

    // K1: comm -> A region (scratch); K2 consumes + overwrites in place.
    k1_comm<<<dim3(8, 16, 32), 256, 0, stream>>>(Q, K, Aout);
    k2_fuse<<<dim3(4, 8, 32), 256, 0, stream>>>(Aout, Vv, phi, u, hard, lg, ltau, ltc, Vout, ent);
}

// Round 2
// 362.882 us; speedup vs baseline: 2.0030x; 2.0030x over previous
//
#include <hip/hip_runtime.h>
#include <math.h>

#define Bn 4
#define Ln 1024
#define Sn 1024
#define Hn 8
#define En 64

typedef __attribute__((ext_vector_type(4))) float f32x4;
typedef __attribute__((ext_vector_type(8))) short s16x8;
typedef __attribute__((ext_vector_type(4))) short s16x4;

__device__ __forceinline__ short f2bf(float x) {
    unsigned u = __float_as_uint(x);
    unsigned r = (u + 0x7FFFu + ((u >> 16) & 1u)) >> 16;
    return (short)r;
}
__device__ __forceinline__ float bf2f(short s) {
    return __uint_as_float(((unsigned)(unsigned short)s) << 16);
}
__device__ __forceinline__ float frcp(float x) { return __builtin_amdgcn_rcpf(x); }

// ---------------------------------------------------------------------------
// Fused LieAttention: per (b,h,64-l-tile) block, loop 16 chunks of 64 s:
//   comm tile = Q_lt K_st^T - K_lt Q_st^T  via 2-term split-bf16 MFMA (6 chains)
//   -> tanh/gelu/gumbel-sigmoid/hard-mask chain in C-layout -> write A
//   -> entropy row-partials in regs
//   -> P (bf16) -> LDS round trip -> PV MFMA with value^T staged in LDS
// LDS: 4x B-side tiles (K/Q hi+lo) + value^T + per-wave P = 55.3 KB
// -> 2 blocks/CU. A-side (Q_lt, K_lt) frags live in registers (split once).
// ---------------------------------------------------------------------------
__global__ __launch_bounds__(256, 2) void fused_lie(
    const float* __restrict__ Q, const float* __restrict__ K,
    const float* __restrict__ V, const float* __restrict__ phi,
    const float* __restrict__ u, const float* __restrict__ hard,
    const float* __restrict__ p_lg, const float* __restrict__ p_lt,
    const float* __restrict__ p_ltc,
    float* __restrict__ Aout, float* __restrict__ Vout,
    float* __restrict__ entOut) {
    __shared__ __align__(16) short kbh[64 * 72];
    __shared__ __align__(16) short kbl[64 * 72];
    __shared__ __align__(16) short qbh[64 * 72];
    __shared__ __align__(16) short qbl[64 * 72];
    __shared__ __align__(16) short vbt[64 * 72];
    __shared__ __align__(16) short plds[4][16 * 72];

    const int lt = blockIdx.x, h = blockIdx.y, b = blockIdx.z;
    const int tid = threadIdx.x;
    const int w = tid >> 6;          // wave 0..3
    const int lane = tid & 63;
    const int q = lane >> 4;         // quad 0..3
    const int n = lane & 15;
    const int l0 = lt * 64;

    const float gain = fminf(fmaxf(expf(p_lg[0]), 1e-3f), 1000.0f);
    const float tauc = fminf(fmaxf(expf(p_ltc[0]), 1e-3f), 10.0f);
    const float c1 = gain / tauc;
    const float tau = fminf(fmaxf(expf(p_lt[0]), 0.1f), 5.0f);
    const float itau = 1.0f / tau;

    // ---- A-side fragments in registers: Q_lt (hi,lo), -K_lt (hi,lo) ----
    s16x8 QAh[2], QAl[2], KAh[2], KAl[2];
    {
        const int la = l0 + w * 16 + n;   // A-frag row = lane&15
        const float* qrow = Q + (((size_t)b * Ln + la) * Hn + h) * En;
        const float* krow = K + (((size_t)b * Sn + la) * Hn + h) * En;
#pragma unroll
        for (int kh = 0; kh < 2; ++kh) {
            const int e0 = q * 8 + kh * 32;   // A-frag k = quad*8 + j (+32/khalf)
            float qe[8], ke[8];
            *(f32x4*)(qe) = *(const f32x4*)(qrow + e0);
            *(f32x4*)(qe + 4) = *(const f32x4*)(qrow + e0 + 4);
            *(f32x4*)(ke) = *(const f32x4*)(krow + e0);
            *(f32x4*)(ke + 4) = *(const f32x4*)(krow + e0 + 4);
            s16x8 qh8, ql8, kh8, kl8;
#pragma unroll
            for (int j = 0; j < 8; ++j) {
                short hq = f2bf(qe[j]);
                qh8[j] = hq; ql8[j] = f2bf(qe[j] - bf2f(hq));
                float nk = -ke[j];
                short hk = f2bf(nk);
                kh8[j] = hk; kl8[j] = f2bf(nk - bf2f(hk));
            }
            QAh[kh] = qh8; QAl[kh] = ql8; KAh[kh] = kh8; KAl[kh] = kl8;
        }
    }

    f32x4 accV[4];
#pragma unroll
    for (int i = 0; i < 4; ++i) accV[i] = (f32x4){0.f, 0.f, 0.f, 0.f};
    float entp[4] = {0.f, 0.f, 0.f, 0.f};

    for (int st = 0; st < 16; ++st) {
        const int s0 = st * 64;
        if (st) __syncthreads();   // all waves done reading previous B tiles

        // ---- stage K_st, Q_st (hi+lo) row-major [s][e] ----
#pragma unroll
        for (int i = 0; i < 4; ++i) {
            int idx = tid + 256 * i;
            int row = idx >> 4;
            int c4 = (idx & 15) << 2;
            f32x4 kv = *(const f32x4*)(K + (((size_t)b * Sn + s0 + row) * Hn + h) * En + c4);
            f32x4 qv = *(const f32x4*)(Q + (((size_t)b * Ln + s0 + row) * Hn + h) * En + c4);
            s16x4 kh4, kl4, qh4, ql4;
#pragma unroll
            for (int j = 0; j < 4; ++j) {
                short t = f2bf(kv[j]); kh4[j] = t; kl4[j] = f2bf(kv[j] - bf2f(t));
                short t2 = f2bf(qv[j]); qh4[j] = t2; ql4[j] = f2bf(qv[j] - bf2f(t2));
            }
            int o = row * 72 + c4;
            *(s16x4*)&kbh[o] = kh4; *(s16x4*)&kbl[o] = kl4;
            *(s16x4*)&qbh[o] = qh4; *(s16x4*)&qbl[o] = ql4;
        }
        // ---- stage value^T: vbt[d][s] bf16 ----
#pragma unroll
        for (int i = 0; i < 4; ++i) {
            int sg = (tid >> 6) + 4 * i;   // 0..15, s-group of 4
            int d = tid & 63;
            s16x4 vv;
#pragma unroll
            for (int jj = 0; jj < 4; ++jj) {
                float x = V[(((size_t)b * Sn + s0 + sg * 4 + jj) * Hn + h) * En + d];
                vv[jj] = f2bf(x);
            }
            *(s16x4*)&vbt[d * 72 + sg * 4] = vv;
        }
        __syncthreads();

        // ---- comm tile via 6 split-bf16 MFMA chains ----
        f32x4 acc[4];
#pragma unroll
        for (int i = 0; i < 4; ++i) acc[i] = (f32x4){0.f, 0.f, 0.f, 0.f};
#pragma unroll
        for (int kh = 0; kh < 2; ++kh) {
#pragma unroll
            for (int sub = 0; sub < 4; ++sub) {
                const int off = (sub * 16 + n) * 72 + q * 8 + kh * 32;
                s16x8 KBh = *(const s16x8*)&kbh[off];
                s16x8 KBl = *(const s16x8*)&kbl[off];
                s16x8 QBh = *(const s16x8*)&qbh[off];
                s16x8 QBl = *(const s16x8*)&qbl[off];
                f32x4 a = acc[sub];
                a = __builtin_amdgcn_mfma_f32_16x16x32_bf16(QAh[kh], KBh, a, 0, 0, 0);
                a = __builtin_amdgcn_mfma_f32_16x16x32_bf16(QAh[kh], KBl, a, 0, 0, 0);
                a = __builtin_amdgcn_mfma_f32_16x16x32_bf16(QAl[kh], KBh, a, 0, 0, 0);
                a = __builtin_amdgcn_mfma_f32_16x16x32_bf16(KAh[kh], QBh, a, 0, 0, 0);
                a = __builtin_amdgcn_mfma_f32_16x16x32_bf16(KAh[kh], QBl, a, 0, 0, 0);
                a = __builtin_amdgcn_mfma_f32_16x16x32_bf16(KAl[kh], QBh, a, 0, 0, 0);
                acc[sub] = a;
            }
        }

        // ---- elementwise chain in C-layout (row m=q*4+r, col n) ----
        const int lbase = l0 + w * 16 + q * 4;
#pragma unroll
        for (int sub = 0; sub < 4; ++sub) {
            const int s = s0 + sub * 16 + n;
#pragma unroll
            for (int r = 0; r < 4; ++r) {
                const int l = lbase + r;
                const size_t pidx = ((size_t)h * Ln + l) * (size_t)Sn + s;
                float ph = phi[pidx];
                float uu = u[pidx];
                float hm = hard[(size_t)l * Sn + s];
                float cm = acc[sub][r];
                // tanh(c1*cm) = 1 - 2/(exp(2*c1*cm)+1)
                float e2 = __expf(2.0f * c1 * cm);
                float x = 1.0f - 2.0f * frcp(e2 + 1.0f);
                // exact gelu
                float g = 0.5f * x * (1.0f + erff(x * 0.70710678118654752f));
                // gumbel-sigmoid mask
                float z = (__logf((uu + 1e-8f) * frcp(1.0f - uu + 1e-8f)) + ph) * itau;
                float m = frcp(1.0f + __expf(-z));
                float att = 0.125f * g * m * hm;
                Aout[(((size_t)b * Hn + h) * Ln + l) * (size_t)Sn + s] = att;
                entp[r] += att * __logf(fmaxf(att, 1e-8f));
                plds[w][(q * 4 + r) * 72 + sub * 16 + n] = f2bf(att);
            }
        }

        // ---- PV: accV += P * value  (P A-layout from LDS, value^T B-frags) ----
        {
            const short* pw = &plds[w][0];
#pragma unroll
            for (int kh = 0; kh < 2; ++kh) {
                s16x8 Pf = *(const s16x8*)&pw[n * 72 + q * 8 + kh * 32];
#pragma unroll
                for (int sub = 0; sub < 4; ++sub) {
                    s16x8 Vf = *(const s16x8*)&vbt[(sub * 16 + n) * 72 + q * 8 + kh * 32];
                    accV[sub] = __builtin_amdgcn_mfma_f32_16x16x32_bf16(Pf, Vf, accV[sub], 0, 0, 0);
                }
            }
        }
    }

    // ---- epilogue: V tile ----
#pragma unroll
    for (int sub = 0; sub < 4; ++sub) {
#pragma unroll
        for (int r = 0; r < 4; ++r) {
            const int l = l0 + w * 16 + q * 4 + r;
            Vout[(((size_t)b * Ln + l) * Hn + h) * En + sub * 16 + n] = accV[sub][r];
        }
    }
    // ---- entropy: reduce over the 16 lanes of each quad ----
#pragma unroll
    for (int r = 0; r < 4; ++r) {
        float v = entp[r];
        v += __shfl_xor(v, 1);
        v += __shfl_xor(v, 2);
        v += __shfl_xor(v, 4);
        v += __shfl_xor(v, 8);
        if (n == 0) {
            float e = -v;
            if (!(e == e)) e = 0.f;
            entOut[((size_t)b * Hn + h) * Ln + l0 + w * 16 + q * 4 + r] = e;
        }
    }
}

extern "C" void kernel_launch(void* const* d_in, const int* in_sizes, int n_in,
                              void* d_out, int out_size, void* d_ws, size_t ws_size,
                              hipStream_t stream) {
    (void)in_sizes; (void)n_in; (void)d_ws; (void)ws_size; (void)out_size;

    const float* Q    = (const float*)d_in[0];   // (B,L,H,E)
    const float* K    = (const float*)d_in[1];   // (B,S,H,E)
    const float* Vv   = (const float*)d_in[2];   // (B,S,H,E)
    const float* phi  = (const float*)d_in[3];   // (H,L,S)
    const float* lg   = (const float*)d_in[4];
    const float* ltau = (const float*)d_in[5];
    const float* ltc  = (const float*)d_in[6];
    const float* hard = (const float*)d_in[7];   // (L,S)
    const float* u    = (const float*)d_in[8];   // (H,L,S)

    float* out  = (float*)d_out;
    float* Vout = out;                                 // B*L*H*E
    float* Aout = out + (size_t)Bn * Ln * Hn * En;     // B*H*L*S
    float* ent  = Aout + (size_t)Bn * Hn * Ln * Sn;    // B*H*L

    fused_lie<<<dim3(16, Hn, Bn), 256, 0, stream>>>(Q, K, Vv, phi, u, hard,
                                                    lg, ltau, ltc, Aout, Vout, ent);
}

// Round 3
// 331.126 us; speedup vs baseline: 2.1951x; 1.0959x over previous
//
#include <hip/hip_runtime.h>
#include <math.h>

#define Bn 4
#define Ln 1024
#define Sn 1024
#define Hn 8
#define En 64

typedef __attribute__((ext_vector_type(4))) float f32x4;
typedef __attribute__((ext_vector_type(8))) _Float16 h16x8;
typedef __attribute__((ext_vector_type(4))) _Float16 h16x4;

__device__ __forceinline__ float frcp(float x) { return __builtin_amdgcn_rcpf(x); }

__device__ __forceinline__ void gl_lds16(const void* g, void* l) {
    __builtin_amdgcn_global_load_lds(
        (const __attribute__((address_space(1))) unsigned int*)g,
        (__attribute__((address_space(3))) unsigned int*)l, 16, 0, 0);
}

// ---------------------------------------------------------------------------
// prep: split Q,K fp32 -> f16 hi/lo in [bh][row][e] XOR-swizzled rows (16B
// chunk c stored at c^(row&7)); V -> f16 transposed tiles [bh][stile][d][64]
// with the same swizzle. Makes the hot kernel's staging pure global_load_lds.
// ---------------------------------------------------------------------------
__global__ __launch_bounds__(256) void prep(
    const float* __restrict__ Q, const float* __restrict__ K,
    const float* __restrict__ V,
    _Float16* __restrict__ Qh, _Float16* __restrict__ Ql,
    _Float16* __restrict__ Kh, _Float16* __restrict__ Kl,
    _Float16* __restrict__ Vt) {
    __shared__ float vlds[64][69];
    const int st = blockIdx.x;   // s-tile 0..15
    const int bh = blockIdx.y;   // 0..31
    const int b = bh >> 3, h = bh & 7;
    const int tid = threadIdx.x;
    const int s0 = st * 64;

#pragma unroll
    for (int i = 0; i < 4; ++i) {
        int idx = tid + 256 * i;     // 0..1023
        int r = idx >> 4;            // row 0..63
        int c4 = (idx & 15) << 2;    // e 0,4..60
        size_t gin = (((size_t)b * Ln + s0 + r) * Hn + h) * En + c4;
        f32x4 qv = *(const f32x4*)(Q + gin);
        f32x4 kv = *(const f32x4*)(K + gin);
        f32x4 vv = *(const f32x4*)(V + gin);
        vlds[r][c4 + 0] = vv.x; vlds[r][c4 + 1] = vv.y;
        vlds[r][c4 + 2] = vv.z; vlds[r][c4 + 3] = vv.w;
        h16x4 qh4, ql4, kh4, kl4;
#pragma unroll
        for (int j = 0; j < 4; ++j) {
            float x = qv[j];
            _Float16 hx = (_Float16)x;
            qh4[j] = hx; ql4[j] = (_Float16)(x - (float)hx);
            float y = kv[j];
            _Float16 hy = (_Float16)y;
            kh4[j] = hy; kl4[j] = (_Float16)(y - (float)hy);
        }
        size_t ob = ((size_t)bh * 1024 + s0 + r) * 64 + ((((c4 >> 3) ^ (r & 7)) << 3) + (c4 & 7));
        *(h16x4*)(Qh + ob) = qh4; *(h16x4*)(Ql + ob) = ql4;
        *(h16x4*)(Kh + ob) = kh4; *(h16x4*)(Kl + ob) = kl4;
    }
    __syncthreads();
    // transposed V tile: Vt[bh][st][d][s-local], swizzled rows
#pragma unroll
    for (int i = 0; i < 4; ++i) {
        int idx = tid + 256 * i;
        int d = idx >> 4;            // 0..63
        int sg = (idx & 15) << 2;    // 0..60
        h16x4 v4;
#pragma unroll
        for (int j = 0; j < 4; ++j) v4[j] = (_Float16)vlds[sg + j][d];
        size_t ob = (((size_t)bh * 16 + st) * 64 + d) * 64 + ((((sg >> 3) ^ (d & 7)) << 3) + (sg & 7));
        *(h16x4*)(Vt + ob) = v4;
    }
}

// ---------------------------------------------------------------------------
// fused: per (b,h,64-l-tile, s-half) block, 8 chunks of 64 s:
//   global_load_lds staging of pre-split K/Q hi/lo + V^T (swizzled, no VALU)
//   comm = acc1 - acc2 via 6 f16-split MFMA chains (2 accumulators)
//   tanh -> tanh-GELU -> gumbel-sigmoid -> hard mask -> A store + entropy
//   P -> LDS -> PV f16 MFMA; V and entropy finalized with atomics.
// LDS 49 KB, launch_bounds(256,3) -> 3 blocks/CU; grid 1024 blocks.
// ---------------------------------------------------------------------------
__global__ __launch_bounds__(256, 3) void fused_lie(
    const _Float16* __restrict__ Qh, const _Float16* __restrict__ Ql,
    const _Float16* __restrict__ Kh, const _Float16* __restrict__ Kl,
    const _Float16* __restrict__ Vt,
    const float* __restrict__ phi, const float* __restrict__ u,
    const float* __restrict__ hard,
    const float* __restrict__ p_lg, const float* __restrict__ p_lt,
    const float* __restrict__ p_ltc,
    float* __restrict__ Aout, float* __restrict__ Vout,
    float* __restrict__ entOut) {
    __shared__ __align__(16) _Float16 kbh[4096];
    __shared__ __align__(16) _Float16 kbl[4096];
    __shared__ __align__(16) _Float16 qbh[4096];
    __shared__ __align__(16) _Float16 qbl[4096];
    __shared__ __align__(16) _Float16 vbt[4096];
    __shared__ __align__(16) _Float16 plds[4][16 * 72];

    const int bx = blockIdx.x;
    const int lt = bx >> 1, sh = bx & 1;
    const int h = blockIdx.y, b = blockIdx.z;
    const int bh = b * Hn + h;
    const int tid = threadIdx.x;
    const int w = tid >> 6;
    const int lane = tid & 63;
    const int q = lane >> 4;
    const int n = lane & 15;
    const int swz = n & 7;
    const int l0 = lt * 64;

    const float gain = fminf(fmaxf(expf(p_lg[0]), 1e-3f), 1000.0f);
    const float tauc = fminf(fmaxf(expf(p_ltc[0]), 1e-3f), 10.0f);
    const float c2 = 2.0f * gain / tauc;
    const float tau = fminf(fmaxf(expf(p_lt[0]), 0.1f), 5.0f);
    const float itau = 1.0f / tau;

    // A-side fragments (registers): rows l0+w*16+n, k = q*8+j (+32*kh)
    h16x8 QAh[2], QAl[2], KAh[2], KAl[2];
    {
        const size_t ab = ((size_t)bh * 1024 + l0 + w * 16 + n) * 64;
#pragma unroll
        for (int kh = 0; kh < 2; ++kh) {
            size_t off = ab + (((q + kh * 4) ^ swz) << 3);
            QAh[kh] = *(const h16x8*)(Qh + off);
            QAl[kh] = *(const h16x8*)(Ql + off);
            KAh[kh] = *(const h16x8*)(Kh + off);
            KAl[kh] = *(const h16x8*)(Kl + off);
        }
    }

    f32x4 accV[4];
#pragma unroll
    for (int i = 0; i < 4; ++i) accV[i] = (f32x4){0.f, 0.f, 0.f, 0.f};
    float entp[4] = {0.f, 0.f, 0.f, 0.f};

    const int lbase = l0 + w * 16 + q * 4;

    for (int stc = 0; stc < 8; ++stc) {
        const int st = sh * 8 + stc;
        const int s0 = st * 64;
        if (stc) __syncthreads();

        // ---- async staging: 5 tiles x 8KB via global_load_lds dwordx4 ----
        {
            const size_t sb = ((size_t)bh * 1024 + s0) * 64;   // halves
            const size_t vb = (((size_t)bh * 16 + st) * 64) * 64;
#pragma unroll
            for (int i = 0; i < 2; ++i) {
                int hoff = w * 1024 + i * 512 + lane * 8;      // halves
                gl_lds16(Kh + sb + hoff, kbh + hoff);
                gl_lds16(Kl + sb + hoff, kbl + hoff);
                gl_lds16(Qh + sb + hoff, qbh + hoff);
                gl_lds16(Ql + sb + hoff, qbl + hoff);
                gl_lds16(Vt + vb + hoff, vbt + hoff);
            }
        }
        __syncthreads();

        // ---- QK: acc1 = Q·K^T, acc2 = K·Q^T (f16 split, 3 chains each) ----
        f32x4 a1[4], a2[4];
#pragma unroll
        for (int i = 0; i < 4; ++i) {
            a1[i] = (f32x4){0.f, 0.f, 0.f, 0.f};
            a2[i] = (f32x4){0.f, 0.f, 0.f, 0.f};
        }
#pragma unroll
        for (int kh = 0; kh < 2; ++kh) {
#pragma unroll
            for (int sub = 0; sub < 4; ++sub) {
                const int off = (sub * 16 + n) * 64 + (((q + kh * 4) ^ swz) << 3);
                h16x8 KBh = *(const h16x8*)&kbh[off];
                h16x8 KBl = *(const h16x8*)&kbl[off];
                h16x8 QBh = *(const h16x8*)&qbh[off];
                h16x8 QBl = *(const h16x8*)&qbl[off];
                f32x4 x1 = a1[sub], x2 = a2[sub];
                x1 = __builtin_amdgcn_mfma_f32_16x16x32_f16(QAh[kh], KBh, x1, 0, 0, 0);
                x1 = __builtin_amdgcn_mfma_f32_16x16x32_f16(QAh[kh], KBl, x1, 0, 0, 0);
                x1 = __builtin_amdgcn_mfma_f32_16x16x32_f16(QAl[kh], KBh, x1, 0, 0, 0);
                x2 = __builtin_amdgcn_mfma_f32_16x16x32_f16(KAh[kh], QBh, x2, 0, 0, 0);
                x2 = __builtin_amdgcn_mfma_f32_16x16x32_f16(KAh[kh], QBl, x2, 0, 0, 0);
                x2 = __builtin_amdgcn_mfma_f32_16x16x32_f16(KAl[kh], QBh, x2, 0, 0, 0);
                a1[sub] = x1; a2[sub] = x2;
            }
        }

        // ---- elementwise chain (C-layout: row q*4+r, col sub*16+n) ----
#pragma unroll
        for (int sub = 0; sub < 4; ++sub) {
            const int s = s0 + sub * 16 + n;
#pragma unroll
            for (int r = 0; r < 4; ++r) {
                const int l = lbase + r;
                const size_t pidx = ((size_t)h * Ln + l) * (size_t)Sn + s;
                float ph = phi[pidx];
                float uu = u[pidx];
                float hm = hard[(size_t)l * Sn + s];
                float cm = a1[sub][r] - a2[sub][r];
                // tanh(c1*cm) = 1 - 2/(exp(c2*cm)+1)
                float x = 1.0f - 2.0f * frcp(__expf(c2 * cm) + 1.0f);
                // tanh-form gelu: x * sigmoid(1.5957691*(x + 0.044715 x^3))
                float t = x * fmaf(0.044715f * x, x, 1.0f);
                float g = x * frcp(1.0f + __expf(-1.59576912161f * t));
                // gumbel-sigmoid mask
                float z = (__logf((uu + 1e-8f) * frcp(1.0f - uu + 1e-8f)) + ph) * itau;
                float m = frcp(1.0f + __expf(-z));
                float att = 0.125f * g * m * hm;
                Aout[(((size_t)b * Hn + h) * Ln + l) * (size_t)Sn + s] = att;
                entp[r] += att * __logf(fmaxf(att, 1e-8f));
                plds[w][(q * 4 + r) * 72 + sub * 16 + n] = (_Float16)att;
            }
        }

        // ---- PV: accV += P · V (P A-frags from LDS, V^T B-frags) ----
        {
            const _Float16* pw = &plds[w][0];
#pragma unroll
            for (int kh = 0; kh < 2; ++kh) {
                h16x8 Pf = *(const h16x8*)&pw[n * 72 + q * 8 + kh * 32];
#pragma unroll
                for (int sub = 0; sub < 4; ++sub) {
                    h16x8 Vf = *(const h16x8*)&vbt[(sub * 16 + n) * 64 + (((q + kh * 4) ^ swz) << 3)];
                    accV[sub] = __builtin_amdgcn_mfma_f32_16x16x32_f16(Pf, Vf, accV[sub], 0, 0, 0);
                }
            }
        }
    }

    // ---- epilogue: V partial sums via atomics (2 s-half blocks per l-tile) ----
#pragma unroll
    for (int sub = 0; sub < 4; ++sub) {
#pragma unroll
        for (int r = 0; r < 4; ++r) {
            const int l = l0 + w * 16 + q * 4 + r;
            atomicAdd(Vout + (((size_t)b * Ln + l) * Hn + h) * En + sub * 16 + n, accV[sub][r]);
        }
    }
    // ---- entropy: quad-row reduce over 16 lanes, atomic partial ----
#pragma unroll
    for (int r = 0; r < 4; ++r) {
        float v = entp[r];
        v += __shfl_xor(v, 1);
        v += __shfl_xor(v, 2);
        v += __shfl_xor(v, 4);
        v += __shfl_xor(v, 8);
        if (n == 0) {
            atomicAdd(entOut + ((size_t)b * Hn + h) * Ln + lbase + r, -v);
        }
    }
}

extern "C" void kernel_launch(void* const* d_in, const int* in_sizes, int n_in,
                              void* d_out, int out_size, void* d_ws, size_t ws_size,
                              hipStream_t stream) {
    (void)in_sizes; (void)n_in; (void)ws_size; (void)out_size;

    const float* Q    = (const float*)d_in[0];   // (B,L,H,E)
    const float* K    = (const float*)d_in[1];   // (B,S,H,E)
    const float* Vv   = (const float*)d_in[2];   // (B,S,H,E)
    const float* phi  = (const float*)d_in[3];   // (H,L,S)
    const float* lg   = (const float*)d_in[4];
    const float* ltau = (const float*)d_in[5];
    const float* ltc  = (const float*)d_in[6];
    const float* hard = (const float*)d_in[7];   // (L,S)
    const float* u    = (const float*)d_in[8];   // (H,L,S)

    float* out  = (float*)d_out;
    float* Vout = out;                                 // B*L*H*E
    float* Aout = out + (size_t)Bn * Ln * Hn * En;     // B*H*L*S
    float* ent  = Aout + (size_t)Bn * Hn * Ln * Sn;    // B*H*L

    const size_t NE = (size_t)32 * 1024 * 64;          // 2.1M halves per array
    _Float16* Qh = (_Float16*)d_ws;
    _Float16* Ql = Qh + NE;
    _Float16* Kh = Ql + NE;
    _Float16* Kl = Kh + NE;
    _Float16* Vt = Kl + NE;

    hipMemsetAsync(Vout, 0, (size_t)Bn * Ln * Hn * En * sizeof(float), stream);
    hipMemsetAsync(ent, 0, (size_t)Bn * Hn * Ln * sizeof(float), stream);
    prep<<<dim3(16, 32), 256, 0, stream>>>(Q, K, Vv, Qh, Ql, Kh, Kl, Vt);
    fused_lie<<<dim3(32, Hn, Bn), 256, 0, stream>>>(Qh, Ql, Kh, Kl, Vt, phi, u, hard,
                                                    lg, ltau, ltc, Aout, Vout, ent);
}